// Round 1
// baseline (774.795 us; speedup 1.0000x reference)
//
#include <hip/hip_runtime.h>
#include <stdint.h>

// ---------------- problem constants ----------------
#define B_N   1024
#define D_N   512
#define C_N   50000
#define K_N   3
#define CP    50016            // classes padded to multiple of 32
#define NROWS (CP * 4)         // 200064 padded weight rows (4 = K padded)

#define S_SCALE 50.0f
#define COS_M   0.8775825619f  // cos(0.5)
#define SIN_M   0.4794255386f  // sin(0.5)
#define EPS_C   1e-7f

typedef __bf16 bf16_t;
typedef bf16_t bf16x8 __attribute__((ext_vector_type(8)));
typedef float  f32x4  __attribute__((ext_vector_type(4)));

__device__ __forceinline__ float wave_reduce_sum(float v) {
#pragma unroll
    for (int m = 1; m < 64; m <<= 1) v += __shfl_xor(v, m, 64);
    return v;
}

__device__ __forceinline__ void async_copy16(const void* g, void* l) {
    __builtin_amdgcn_global_load_lds(
        (const __attribute__((address_space(1))) void*)g,
        (__attribute__((address_space(3))) void*)l,
        16, 0, 0);
}

// ---------------- prepass: normalize embeddings -> bf16 ----------------
// one wave per row, 4 rows/block, grid 256
__global__ void k_norm_emb(const float* __restrict__ x, bf16_t* __restrict__ y) {
    const int row  = blockIdx.x * 4 + (threadIdx.x >> 6);
    const int lane = threadIdx.x & 63;
    const float4* p = (const float4*)(x + (size_t)row * D_N + lane * 8);
    float4 a = p[0], b = p[1];
    float s = a.x*a.x + a.y*a.y + a.z*a.z + a.w*a.w
            + b.x*b.x + b.y*b.y + b.z*b.z + b.w*b.w;
    s = wave_reduce_sum(s);
    float sc = 1.0f / fmaxf(sqrtf(s), 1e-12f);
    bf16x8 o;
    o[0] = (bf16_t)(a.x * sc); o[1] = (bf16_t)(a.y * sc);
    o[2] = (bf16_t)(a.z * sc); o[3] = (bf16_t)(a.w * sc);
    o[4] = (bf16_t)(b.x * sc); o[5] = (bf16_t)(b.y * sc);
    o[6] = (bf16_t)(b.z * sc); o[7] = (bf16_t)(b.w * sc);
    *(bf16x8*)(y + (size_t)row * D_N + lane * 8) = o;
}

// ---------------- prepass: normalize weight rows -> bf16, K padded 3->4 ----------------
// input row r (r < 150000) goes to padded row r + r/3  (== (r/3)*4 + r%3)
// grid 37500
__global__ void k_norm_w(const float* __restrict__ x, bf16_t* __restrict__ y) {
    const int row  = blockIdx.x * 4 + (threadIdx.x >> 6);
    const int lane = threadIdx.x & 63;
    const float4* p = (const float4*)(x + (size_t)row * D_N + lane * 8);
    float4 a = p[0], b = p[1];
    float s = a.x*a.x + a.y*a.y + a.z*a.z + a.w*a.w
            + b.x*b.x + b.y*b.y + b.z*b.z + b.w*b.w;
    s = wave_reduce_sum(s);
    float sc = 1.0f / fmaxf(sqrtf(s), 1e-12f);
    const size_t orow = (size_t)row + (size_t)(row / 3);  // padded row index
    bf16x8 o;
    o[0] = (bf16_t)(a.x * sc); o[1] = (bf16_t)(a.y * sc);
    o[2] = (bf16_t)(a.z * sc); o[3] = (bf16_t)(a.w * sc);
    o[4] = (bf16_t)(b.x * sc); o[5] = (bf16_t)(b.y * sc);
    o[6] = (bf16_t)(b.z * sc); o[7] = (bf16_t)(b.w * sc);
    *(bf16x8*)(y + orow * D_N + lane * 8) = o;
}

// ---------------- main GEMM + fused max/margin epilogue ----------------
// D[m][n]: m = padded weight row (class*4 + subcenter), n = batch.
// 16x16x32 bf16 MFMA, block tile 128 rows x 128 batches, BK=32, m97-style
// global_load_lds staging. C/D layout: col=lane&15 (batch), row=quad*4+reg
// -> each lane's 4 regs per tile = 4 subcenters of ONE class: max in-lane.
__global__ __launch_bounds__(256) void k_gemm(const bf16_t* __restrict__ Wn,
                                              const bf16_t* __restrict__ En,
                                              const int*    __restrict__ labels,
                                              float*        __restrict__ out) {
    __shared__ bf16_t Ws[128][32];
    __shared__ bf16_t Es[128][32];
    __shared__ float  So[128][33];   // +1 pad: transpose staging, conflict-free

    const int tid  = threadIdx.x;
    const int wave = tid >> 6, lane = tid & 63;
    const int wr = wave >> 1, wc = wave & 1;   // 2x2 wave grid, each 64x64
    const int col  = lane & 15, quad = lane >> 4;

    const int    b0 = blockIdx.x * 128;            // batch tile base
    const size_t n0 = (size_t)blockIdx.y * 128;    // padded weight-row base
    const int    c0 = blockIdx.y * 32;             // class tile base

    f32x4 acc[4][4] = {};

    const int srow   = lane >> 2;        // 0..15 row within 16-row slab
    const int schunk = (lane & 3) * 8;   // bf16 element offset within row

    for (int kk = 0; kk < D_N; kk += 32) {
        __syncthreads();
#pragma unroll
        for (int i = 0; i < 2; ++i) {
            const int rb = i * 64 + wave * 16;     // wave-uniform slab base
            const bf16_t* ga = Wn + (n0 + rb + srow) * D_N + kk + schunk;
            async_copy16(ga, &Ws[rb][0]);
            const bf16_t* gb = En + (size_t)(b0 + rb + srow) * D_N + kk + schunk;
            async_copy16(gb, &Es[rb][0]);
        }
        __syncthreads();

        bf16x8 af[4], bfr[4];
#pragma unroll
        for (int t = 0; t < 4; ++t) {
            af[t]  = *(const bf16x8*)&Ws[wr * 64 + t * 16 + col][quad * 8];
            bfr[t] = *(const bf16x8*)&Es[wc * 64 + t * 16 + col][quad * 8];
        }
#pragma unroll
        for (int ti = 0; ti < 4; ++ti)
#pragma unroll
            for (int tj = 0; tj < 4; ++tj)
                acc[ti][tj] = __builtin_amdgcn_mfma_f32_16x16x32_bf16(
                    af[ti], bfr[tj], acc[ti][tj], 0, 0, 0);
    }

    // ---- epilogue: max over 3 real subcenters (reg 0..2), margin, stage ----
    int lab[4];
#pragma unroll
    for (int tj = 0; tj < 4; ++tj) lab[tj] = labels[b0 + wc * 64 + tj * 16 + col];

#pragma unroll
    for (int ti = 0; ti < 4; ++ti) {
        const int c_local = wr * 16 + ti * 4 + quad;   // 0..31
        const int c       = c0 + c_local;
#pragma unroll
        for (int tj = 0; tj < 4; ++tj) {
            float v = fmaxf(fmaxf(acc[ti][tj][0], acc[ti][tj][1]), acc[ti][tj][2]);
            if (c == lab[tj]) {
                float x = fminf(fmaxf(v, -1.0f + EPS_C), 1.0f - EPS_C);
                v = x * COS_M - sqrtf(fmaxf(1.0f - x * x, 0.0f)) * SIN_M;
            }
            So[wc * 64 + tj * 16 + col][c_local] = S_SCALE * v;
        }
    }
    __syncthreads();

    // ---- coalesced write-out: 128 batches x 32 classes ----
    const int row  = tid >> 1;
    const int half = tid & 1;
    const size_t gbase = (size_t)(b0 + row) * C_N;
#pragma unroll
    for (int q = 0; q < 4; ++q) {
        const int ci = half * 16 + q * 4;
        const int c  = c0 + ci;
        if (c < C_N) {
            float4 o = make_float4(So[row][ci], So[row][ci + 1],
                                   So[row][ci + 2], So[row][ci + 3]);
            *(float4*)(out + gbase + c) = o;
        }
    }
}

// ---------------- fallback path (ws too small for bf16 weights) ----------------
__global__ void k_fb_norms(const float* __restrict__ emb, const float* __restrict__ w,
                           float* __restrict__ einv, float* __restrict__ winv) {
    const int row  = blockIdx.x * 4 + (threadIdx.x >> 6);
    const int lane = threadIdx.x & 63;
    if (row >= B_N + C_N * K_N) return;
    const float* src = (row < B_N) ? (emb + (size_t)row * D_N)
                                   : (w + (size_t)(row - B_N) * D_N);
    const float4* p = (const float4*)(src + lane * 8);
    float4 a = p[0], b = p[1];
    float s = a.x*a.x + a.y*a.y + a.z*a.z + a.w*a.w
            + b.x*b.x + b.y*b.y + b.z*b.z + b.w*b.w;
    s = wave_reduce_sum(s);
    if (lane == 0) {
        float sc = 1.0f / fmaxf(sqrtf(s), 1e-12f);
        if (row < B_N) einv[row] = sc; else winv[row - B_N] = sc;
    }
}

__global__ void k_fb_gemm(const float* __restrict__ emb, const float* __restrict__ w,
                          const int* __restrict__ labels, const float* __restrict__ einv,
                          const float* __restrict__ winv, float* __restrict__ out) {
    const int b = blockIdx.x;
    const int c = blockIdx.y * 256 + threadIdx.x;
    if (c >= C_N) return;
    const float4* e4 = (const float4*)(emb + (size_t)b * D_N);
    const float es = einv[b];
    float best = -1e30f;
    for (int k = 0; k < K_N; ++k) {
        const float4* w4 = (const float4*)(w + ((size_t)c * K_N + k) * D_N);
        float dot = 0.0f;
#pragma unroll 4
        for (int d = 0; d < D_N / 4; ++d) {
            float4 a = e4[d], bb = w4[d];
            dot += a.x*bb.x + a.y*bb.y + a.z*bb.z + a.w*bb.w;
        }
        dot *= es * winv[c * K_N + k];
        best = fmaxf(best, dot);
    }
    if (c == labels[b]) {
        float x = fminf(fmaxf(best, -1.0f + EPS_C), 1.0f - EPS_C);
        best = x * COS_M - sqrtf(fmaxf(1.0f - x * x, 0.0f)) * SIN_M;
    }
    out[(size_t)b * C_N + c] = S_SCALE * best;
}

// ---------------- launch ----------------
extern "C" void kernel_launch(void* const* d_in, const int* in_sizes, int n_in,
                              void* d_out, int out_size, void* d_ws, size_t ws_size,
                              hipStream_t stream) {
    const float* emb    = (const float*)d_in[0];
    const int*   labels = (const int*)d_in[1];
    const float* weight = (const float*)d_in[2];
    float*       out    = (float*)d_out;

    const size_t offW = (size_t)1 << 20;                      // 1 MB for En
    const size_t need = offW + (size_t)NROWS * D_N * 2;       // + bf16 weights
    if (ws_size >= need) {
        bf16_t* En = (bf16_t*)d_ws;
        bf16_t* Wn = (bf16_t*)((char*)d_ws + offW);
        k_norm_emb<<<B_N / 4, 256, 0, stream>>>(emb, En);
        k_norm_w<<<(C_N * K_N) / 4, 256, 0, stream>>>(weight, Wn);
        k_gemm<<<dim3(B_N / 128, NROWS / 128), 256, 0, stream>>>(Wn, En, labels, out);
    } else {
        float* einv = (float*)d_ws;
        float* winv = einv + B_N;
        k_fb_norms<<<(B_N + C_N * K_N) / 4, 256, 0, stream>>>(emb, weight, einv, winv);
        k_fb_gemm<<<dim3(B_N, (C_N + 255) / 256), 256, 0, stream>>>(emb, weight, labels,
                                                                    einv, winv, out);
    }
}